// Round 3
// baseline (645.439 us; speedup 1.0000x reference)
//
#include <hip/hip_runtime.h>
#include <hip/hip_bf16.h>
#include <cstdint>

#define NLAT 4096
#define NQRY 16384

// jax.nn.gelu default is approximate=True (tanh form)
__device__ __forceinline__ float gelu_tanh(float x) {
    float x3 = x * x * x;
    float u  = 0.7978845608028654f * (x + 0.044715f * x3);
    float e  = __expf(2.0f * u);
    float t  = 1.0f - 2.0f / (e + 1.0f);
    return 0.5f * x * (1.0f + t);
}

__device__ __forceinline__ int lower_bound(const int* __restrict__ a, int n, int v) {
    int lo = 0, hi = n;
    while (lo < hi) {
        int m = (lo + hi) >> 1;
        if (a[m] < v) lo = m + 1; else hi = m;
    }
    return lo;
}

// ---------------------------------------------------------------------------
// Fully fused: one wave (64 threads) per query. No workspace, no atomics.
// Lane j owns channel j of the 64-wide kernel-MLP output and rndata channel j.
// All inputs/outputs are float32 (per reference dtypes).
// ---------------------------------------------------------------------------
__global__ __launch_bounds__(64) void fused_kernel(
    const float* __restrict__ lat,  const float* __restrict__ rnd,
    const float* __restrict__ qc,
    const int* __restrict__ src0, const int* __restrict__ qry0, int E0,
    const int* __restrict__ src1, const int* __restrict__ qry1, int E1,
    const float* __restrict__ Wk0, const float* __restrict__ bk0,
    const float* __restrict__ Wk1, const float* __restrict__ bk1,
    const float* __restrict__ Wk2, const float* __restrict__ bk2,
    const float* __restrict__ Wsw0, const float* __restrict__ bsw0,
    const float* __restrict__ Wsw1, const float* __restrict__ bsw1,
    const float* __restrict__ Wp0, const float* __restrict__ bp0,
    const float* __restrict__ Wp1, const float* __restrict__ bp1,
    float* __restrict__ out)
{
    const int q = blockIdx.x;
    const int lane = threadIdx.x;

    __shared__ __align__(16) float sh1[64];
    __shared__ __align__(16) float sh2[64];
    __shared__ __align__(16) float decs[4][64];

    // ---- preload kernel-MLP weight columns for channel `lane` ----
    float w0c[4];
#pragma unroll
    for (int i = 0; i < 4; i++) w0c[i] = Wk0[i * 64 + lane];
    const float b0  = bk0[lane];
    float w1c[64], w2c[64];
#pragma unroll
    for (int i = 0; i < 64; i++) w1c[i] = Wk1[i * 64 + lane];
    const float b1  = bk1[lane];
#pragma unroll
    for (int i = 0; i < 64; i++) w2c[i] = Wk2[i * 64 + lane];
    const float b2v = bk2[lane];

    const float qc0 = qc[2 * q];
    const float qc1 = qc[2 * q + 1];

    // ---- segment bounds via binary search (qry sorted); lanes 0-3 ----
    int bs = 0;
    if (lane < 2)      bs = lower_bound(qry0, E0, q + lane);
    else if (lane < 4) bs = lower_bound(qry1, E1, q + lane - 2);
    const int lo0 = __shfl(bs, 0), hi0 = __shfl(bs, 1);
    const int lo1 = __shfl(bs, 2), hi1 = __shfl(bs, 3);

    // ---- edge loops (both sets) ----
    float m0[4] = {0.f, 0.f, 0.f, 0.f};
    float m1[4] = {0.f, 0.f, 0.f, 0.f};

    for (int set = 0; set < 2; set++) {
        const int* srcp = set ? src1 : src0;
        const int lo = set ? lo1 : lo0;
        const int hi = set ? hi1 : hi0;
        float a0 = 0.f, a1 = 0.f, a2 = 0.f, a3 = 0.f;

        for (int e = lo; e < hi; e++) {
            const int s = srcp[e];
            const float lc0 = lat[2 * s];
            const float lc1 = lat[2 * s + 1];
            const float r0 = rnd[(size_t)(0 * NLAT + s) * 64 + lane];
            const float r1 = rnd[(size_t)(1 * NLAT + s) * 64 + lane];
            const float r2 = rnd[(size_t)(2 * NLAT + s) * 64 + lane];
            const float r3 = rnd[(size_t)(3 * NLAT + s) * 64 + lane];

            // layer 1: 4 -> 64, gelu
            const float h1 = gelu_tanh(b0 + lc0 * w0c[0] + lc1 * w0c[1]
                                          + qc0 * w0c[2] + qc1 * w0c[3]);
            sh1[lane] = h1;
            __syncthreads();

            // layer 2: 64 -> 64, gelu
            float s0 = b1, s1 = 0.f, s2 = 0.f, s3 = 0.f;
#pragma unroll
            for (int i = 0; i < 64; i += 4) {
                const float4 v = *(const float4*)&sh1[i];
                s0 += v.x * w1c[i];
                s1 += v.y * w1c[i + 1];
                s2 += v.z * w1c[i + 2];
                s3 += v.w * w1c[i + 3];
            }
            const float h2 = gelu_tanh((s0 + s1) + (s2 + s3));
            sh2[lane] = h2;
            __syncthreads();

            // layer 3: 64 -> 64, linear
            float c0 = b2v, c1 = 0.f, c2 = 0.f, c3 = 0.f;
#pragma unroll
            for (int i = 0; i < 64; i += 4) {
                const float4 v = *(const float4*)&sh2[i];
                c0 += v.x * w2c[i];
                c1 += v.y * w2c[i + 1];
                c2 += v.z * w2c[i + 2];
                c3 += v.w * w2c[i + 3];
            }
            const float k = (c0 + c1) + (c2 + c3);

            a0 += k * r0;
            a1 += k * r1;
            a2 += k * r2;
            a3 += k * r3;
            __syncthreads();   // protect sh1/sh2 before next iteration
        }

        const float scale = 1.0f / fmaxf((float)(hi - lo), 1.0f);
        float* m = set ? m1 : m0;
        m[0] = a0 * scale; m[1] = a1 * scale; m[2] = a2 * scale; m[3] = a3 * scale;
    }

    // ---- softmax gate (computed redundantly in every lane; tiny) ----
    float z0 = bsw1[0], z1 = bsw1[1];
#pragma unroll
    for (int i = 0; i < 16; i++) {
        const float h = fmaxf(0.f, qc0 * Wsw0[i] + qc1 * Wsw0[16 + i] + bsw0[i]);
        z0 += h * Wsw1[i * 2 + 0];
        z1 += h * Wsw1[i * 2 + 1];
    }
    const float zm = fmaxf(z0, z1);
    const float e0 = __expf(z0 - zm), e1 = __expf(z1 - zm);
    const float inv = 1.0f / (e0 + e1);
    const float g0 = e0 * inv, g1 = e1 * inv;

    // ---- decoded = g0*d0 + g1*d1 -> LDS ----
#pragma unroll
    for (int b = 0; b < 4; b++) decs[b][lane] = g0 * m0[b] + g1 * m1[b];
    __syncthreads();

    // ---- projection: lane owns hidden cols 4*lane .. 4*lane+3 ----
    float hacc[4][4];  // [t][b]
    {
        const float4 bv = ((const float4*)bp0)[lane];
        const float bt[4] = { bv.x, bv.y, bv.z, bv.w };
#pragma unroll
        for (int t = 0; t < 4; t++)
#pragma unroll
            for (int b = 0; b < 4; b++) hacc[t][b] = bt[t];
    }
#pragma unroll 8
    for (int c = 0; c < 64; c++) {
        const float4 w = ((const float4*)Wp0)[c * 64 + lane];
        const float wf[4] = { w.x, w.y, w.z, w.w };
        const float d0 = decs[0][c], d1 = decs[1][c], d2 = decs[2][c], d3 = decs[3][c];
#pragma unroll
        for (int t = 0; t < 4; t++) {
            hacc[t][0] += wf[t] * d0;
            hacc[t][1] += wf[t] * d1;
            hacc[t][2] += wf[t] * d2;
            hacc[t][3] += wf[t] * d3;
        }
    }
#pragma unroll
    for (int t = 0; t < 4; t++)
#pragma unroll
        for (int b = 0; b < 4; b++) hacc[t][b] = gelu_tanh(hacc[t][b]);

    // out[b][k] partials: Wp1 rows 4*lane+t
    float po[4][4];  // [b][k]
#pragma unroll
    for (int b = 0; b < 4; b++)
#pragma unroll
        for (int k = 0; k < 4; k++) po[b][k] = 0.f;
#pragma unroll
    for (int t = 0; t < 4; t++) {
        const float4 w = ((const float4*)Wp1)[4 * lane + t];
        const float wf[4] = { w.x, w.y, w.z, w.w };
#pragma unroll
        for (int k = 0; k < 4; k++)
#pragma unroll
            for (int b = 0; b < 4; b++) po[b][k] += hacc[t][b] * wf[k];
    }
    // wave-reduce the 16 values
#pragma unroll
    for (int b = 0; b < 4; b++)
#pragma unroll
        for (int k = 0; k < 4; k++) {
            float v = po[b][k];
#pragma unroll
            for (int off = 32; off >= 1; off >>= 1) v += __shfl_xor(v, off, 64);
            po[b][k] = v;
        }

    if (lane == 0) {
#pragma unroll
        for (int b = 0; b < 4; b++)
#pragma unroll
            for (int k = 0; k < 4; k++)
                out[((size_t)b * NQRY + q) * 4 + k] = po[b][k] + bp1[k];
    }
}

// ---------------------------------------------------------------------------
extern "C" void kernel_launch(void* const* d_in, const int* in_sizes, int n_in,
                              void* d_out, int out_size, void* d_ws, size_t ws_size,
                              hipStream_t stream) {
    const float* lat  = (const float*)d_in[0];
    const float* rnd  = (const float*)d_in[1];
    const float* qc   = (const float*)d_in[2];
    const int*   src0 = (const int*)d_in[3];
    const int*   qry0 = (const int*)d_in[4];
    const int*   src1 = (const int*)d_in[5];
    const int*   qry1 = (const int*)d_in[6];
    const float* Wk0 = (const float*)d_in[7],  *bk0 = (const float*)d_in[8];
    const float* Wk1 = (const float*)d_in[9],  *bk1 = (const float*)d_in[10];
    const float* Wk2 = (const float*)d_in[11], *bk2 = (const float*)d_in[12];
    const float* Wsw0 = (const float*)d_in[13], *bsw0 = (const float*)d_in[14];
    const float* Wsw1 = (const float*)d_in[15], *bsw1 = (const float*)d_in[16];
    const float* Wp0 = (const float*)d_in[17], *bp0 = (const float*)d_in[18];
    const float* Wp1 = (const float*)d_in[19], *bp1 = (const float*)d_in[20];

    const int E0 = in_sizes[3];
    const int E1 = in_sizes[5];

    fused_kernel<<<NQRY, 64, 0, stream>>>(
        lat, rnd, qc, src0, qry0, E0, src1, qry1, E1,
        Wk0, bk0, Wk1, bk1, Wk2, bk2,
        Wsw0, bsw0, Wsw1, bsw1, Wp0, bp0, Wp1, bp1,
        (float*)d_out);
}

// Round 4
// 481.873 us; speedup vs baseline: 1.3394x; 1.3394x over previous
//
#include <hip/hip_runtime.h>
#include <hip/hip_bf16.h>
#include <cstdint>

#define NLAT 4096
#define NQRY 16384
#define QPW  2      // queries per block (1 wave)
#define HSTR 68     // padded LDS row stride in f32 (16B-aligned rows, bank-spread)

typedef __attribute__((ext_vector_type(8))) short bh8;    // 8 bf16 (4 VGPRs)
typedef __attribute__((ext_vector_type(4))) float f32x4;  // 4 fp32 acc

union FI { int i[4]; bh8 v; };

// gelu(x) = x * sigmoid(2*0.79788456*(x+0.044715x^3))  (== tanh-form gelu)
__device__ __forceinline__ float gelu_f(float x) {
    float x3 = x * x * x;
    float u2 = 1.5957691216057308f * (x + 0.044715f * x3);
    float r  = __builtin_amdgcn_rcpf(__expf(u2) + 1.0f);
    return x * (1.0f - r);
}

__device__ __forceinline__ int lower_bound(const int* __restrict__ a, int n, int v) {
    int lo = 0, hi = n;
    while (lo < hi) { int m = (lo + hi) >> 1; if (a[m] < v) lo = m + 1; else hi = m; }
    return lo;
}

// pack bf16-truncations of (a -> low short, b -> high short)
__device__ __forceinline__ int pk(float a, float b) {
    return (int)__builtin_amdgcn_perm(__float_as_uint(b), __float_as_uint(a), 0x07060302u);
}

// build hi/lo A-fragments (2 K-steps) from f32 LDS tile sh[row*HSTR+col]
__device__ __forceinline__ void make_afrags(const float* sh, int lane, FI ah[2], FI al[2]) {
    const int m = lane & 15, quad = lane >> 4;
#pragma unroll
    for (int ks = 0; ks < 2; ks++) {
        const float* p = sh + m * HSTR + ks * 32 + quad * 8;
        float4 v0 = *(const float4*)p;
        float4 v1 = *(const float4*)(p + 4);
        float x[8] = {v0.x, v0.y, v0.z, v0.w, v1.x, v1.y, v1.z, v1.w};
#pragma unroll
        for (int jj = 0; jj < 4; jj++) {
            float a = x[2 * jj], b = x[2 * jj + 1];
            ah[ks].i[jj] = pk(a, b);
            float la = a - __uint_as_float(__float_as_uint(a) & 0xFFFF0000u);
            float lb = b - __uint_as_float(__float_as_uint(b) & 0xFFFF0000u);
            al[ks].i[jj] = pk(la, lb);
        }
    }
}

__global__ __launch_bounds__(64, 2) void fused_kernel(
    const float* __restrict__ lat,  const float* __restrict__ rnd,
    const float* __restrict__ qc,
    const int* __restrict__ src0, const int* __restrict__ qry0, int E0,
    const int* __restrict__ src1, const int* __restrict__ qry1, int E1,
    const float* __restrict__ Wk0, const float* __restrict__ bk0,
    const float* __restrict__ Wk1, const float* __restrict__ bk1,
    const float* __restrict__ Wk2, const float* __restrict__ bk2,
    const float* __restrict__ Wsw0, const float* __restrict__ bsw0,
    const float* __restrict__ Wsw1, const float* __restrict__ bsw1,
    const float* __restrict__ Wp0, const float* __restrict__ bp0,
    const float* __restrict__ Wp1, const float* __restrict__ bp1,
    float* __restrict__ out)
{
    const int lane = threadIdx.x;
    const int m16  = lane & 15;
    const int quad = lane >> 4;

    __shared__ __align__(16) float sh[16 * HSTR];   // 16x64 tile, padded
    __shared__ __align__(16) float decs[4][64];

    // ---- W1/W2 hi/lo B-fragments: [layer][ks][nt], gathered once ----
    FI wh[2][2][4], wl[2][2][4];
    {
        const float* Wmat[2] = {Wk1, Wk2};
#pragma unroll
        for (int L = 0; L < 2; L++)
#pragma unroll
            for (int ks = 0; ks < 2; ks++)
#pragma unroll
                for (int nt = 0; nt < 4; nt++)
#pragma unroll
                    for (int jj = 0; jj < 4; jj++) {
                        int k0 = ks * 32 + quad * 8 + 2 * jj;
                        float a = Wmat[L][(size_t)k0 * 64 + nt * 16 + m16];
                        float b = Wmat[L][(size_t)(k0 + 1) * 64 + nt * 16 + m16];
                        wh[L][ks][nt].i[jj] = pk(a, b);
                        float la = a - __uint_as_float(__float_as_uint(a) & 0xFFFF0000u);
                        float lb = b - __uint_as_float(__float_as_uint(b) & 0xFFFF0000u);
                        wl[L][ks][nt].i[jj] = pk(la, lb);
                    }
    }

    // layer-1 weights (channel-per-lane), layer-2/3 bias per nt-tile
    const float w00 = Wk0[0 * 64 + lane];
    const float w01 = Wk0[1 * 64 + lane];
    const float w02 = Wk0[2 * 64 + lane];
    const float w03 = Wk0[3 * 64 + lane];
    const float b0  = bk0[lane];
    float b1v[4], b2v[4];
#pragma unroll
    for (int nt = 0; nt < 4; nt++) {
        b1v[nt] = bk1[16 * nt + m16];
        b2v[nt] = bk2[16 * nt + m16];
    }

    for (int qi = 0; qi < QPW; qi++) {
        const int q = blockIdx.x * QPW + qi;
        const float qc0 = qc[2 * q];
        const float qc1 = qc[2 * q + 1];
        const float base0 = b0 + qc0 * w02 + qc1 * w03;

        // segment bounds (qry sorted)
        int bs = 0;
        if (lane < 2)      bs = lower_bound(qry0, E0, q + lane);
        else if (lane < 4) bs = lower_bound(qry1, E1, q + lane - 2);
        const int lo0 = __shfl(bs, 0, 64), hi0 = __shfl(bs, 1, 64);
        const int lo1 = __shfl(bs, 2, 64), hi1 = __shfl(bs, 3, 64);

        float msum[2][4];

#pragma unroll
        for (int set = 0; set < 2; set++) {
            const int* __restrict__ srcp = set ? src1 : src0;
            const int lo = set ? lo1 : lo0;
            const int hi = set ? hi1 : hi0;
            float a0 = 0.f, a1 = 0.f, a2 = 0.f, a3 = 0.f;

            for (int e0 = lo; e0 < hi; e0 += 16) {
                const int rem = min(16, hi - e0);
                __syncthreads();                       // (a) sh free

                // edge meta: lanes replicate the 16 edges of this batch
                int idx = e0 + m16; if (idx >= hi) idx = hi - 1;
                const int   myS  = srcp[idx];
                const float myl0 = lat[2 * myS];
                const float myl1 = lat[2 * myS + 1];

                // layer 1 (channel-per-lane) -> sh[e][c]
#pragma unroll
                for (int e = 0; e < 16; e++) {
                    float l0 = __shfl(myl0, e, 64);
                    float l1 = __shfl(myl1, e, 64);
                    sh[e * HSTR + lane] = gelu_f(base0 + l0 * w00 + l1 * w01);
                }
                __syncthreads();                       // (b) H1 ready

                FI ah[2], al[2];
                make_afrags(sh, lane, ah, al);
                __syncthreads();                       // (c) H1 reads done

                // layer 2: H2 = gelu(H1@W1 + b1) -> sh
#pragma unroll
                for (int nt = 0; nt < 4; nt++) {
                    f32x4 C = {0.f, 0.f, 0.f, 0.f};
#pragma unroll
                    for (int ks = 0; ks < 2; ks++) {
                        C = __builtin_amdgcn_mfma_f32_16x16x32_bf16(ah[ks].v, wh[0][ks][nt].v, C, 0, 0, 0);
                        C = __builtin_amdgcn_mfma_f32_16x16x32_bf16(al[ks].v, wh[0][ks][nt].v, C, 0, 0, 0);
                        C = __builtin_amdgcn_mfma_f32_16x16x32_bf16(ah[ks].v, wl[0][ks][nt].v, C, 0, 0, 0);
                    }
#pragma unroll
                    for (int r = 0; r < 4; r++)
                        sh[(quad * 4 + r) * HSTR + 16 * nt + m16] = gelu_f(C[r] + b1v[nt]);
                }
                __syncthreads();                       // (d) H2 ready

                make_afrags(sh, lane, ah, al);
                __syncthreads();                       // (e) H2 reads done

                // layer 3: K = H2@W2 + b2 -> sh
#pragma unroll
                for (int nt = 0; nt < 4; nt++) {
                    f32x4 C = {0.f, 0.f, 0.f, 0.f};
#pragma unroll
                    for (int ks = 0; ks < 2; ks++) {
                        C = __builtin_amdgcn_mfma_f32_16x16x32_bf16(ah[ks].v, wh[1][ks][nt].v, C, 0, 0, 0);
                        C = __builtin_amdgcn_mfma_f32_16x16x32_bf16(al[ks].v, wh[1][ks][nt].v, C, 0, 0, 0);
                        C = __builtin_amdgcn_mfma_f32_16x16x32_bf16(ah[ks].v, wl[1][ks][nt].v, C, 0, 0, 0);
                    }
#pragma unroll
                    for (int r = 0; r < 4; r++)
                        sh[(quad * 4 + r) * HSTR + 16 * nt + m16] = C[r] + b2v[nt];
                }
                __syncthreads();                       // (f) k ready

                // accumulate: acc[b] += k[e][lane] * rnd[b][s_e][lane]
                for (int e = 0; e < rem; e++) {
                    const int s = __shfl(myS, e, 64);
                    const float kv = sh[e * HSTR + lane];
                    const float* rp = rnd + (size_t)s * 64 + lane;
                    a0 += kv * rp[0 * NLAT * 64];
                    a1 += kv * rp[1 * NLAT * 64];
                    a2 += kv * rp[2 * NLAT * 64];
                    a3 += kv * rp[3 * NLAT * 64];
                }
            }

            const float scale = __builtin_amdgcn_rcpf(fmaxf((float)(hi - lo), 1.0f));
            msum[set][0] = a0 * scale; msum[set][1] = a1 * scale;
            msum[set][2] = a2 * scale; msum[set][3] = a3 * scale;
        }

        // ---- softmax gate ----
        float z0 = bsw1[0], z1 = bsw1[1];
#pragma unroll
        for (int i = 0; i < 16; i++) {
            const float h = fmaxf(0.f, qc0 * Wsw0[i] + qc1 * Wsw0[16 + i] + bsw0[i]);
            z0 += h * Wsw1[i * 2 + 0];
            z1 += h * Wsw1[i * 2 + 1];
        }
        const float zm = fmaxf(z0, z1);
        const float e0s = __expf(z0 - zm), e1s = __expf(z1 - zm);
        const float inv = __builtin_amdgcn_rcpf(e0s + e1s);
        const float g0 = e0s * inv, g1 = e1s * inv;

        __syncthreads();                 // decs free (prev query's projection done)
#pragma unroll
        for (int b = 0; b < 4; b++) decs[b][lane] = g0 * msum[0][b] + g1 * msum[1][b];
        __syncthreads();

        // ---- projection: lane owns hidden cols 4*lane..4*lane+3 ----
        float hacc[4][4];
        {
            const float4 bv = ((const float4*)bp0)[lane];
            const float bt[4] = { bv.x, bv.y, bv.z, bv.w };
#pragma unroll
            for (int t = 0; t < 4; t++)
#pragma unroll
                for (int b = 0; b < 4; b++) hacc[t][b] = bt[t];
        }
#pragma unroll 8
        for (int c = 0; c < 64; c++) {
            const float4 w = ((const float4*)Wp0)[c * 64 + lane];
            const float wf[4] = { w.x, w.y, w.z, w.w };
            const float d0 = decs[0][c], d1 = decs[1][c], d2 = decs[2][c], d3 = decs[3][c];
#pragma unroll
            for (int t = 0; t < 4; t++) {
                hacc[t][0] += wf[t] * d0;
                hacc[t][1] += wf[t] * d1;
                hacc[t][2] += wf[t] * d2;
                hacc[t][3] += wf[t] * d3;
            }
        }
#pragma unroll
        for (int t = 0; t < 4; t++)
#pragma unroll
            for (int b = 0; b < 4; b++) hacc[t][b] = gelu_f(hacc[t][b]);

        float po[4][4];
#pragma unroll
        for (int b = 0; b < 4; b++)
#pragma unroll
            for (int k = 0; k < 4; k++) po[b][k] = 0.f;
#pragma unroll
        for (int t = 0; t < 4; t++) {
            const float4 w = ((const float4*)Wp1)[4 * lane + t];
            const float wf[4] = { w.x, w.y, w.z, w.w };
#pragma unroll
            for (int k = 0; k < 4; k++)
#pragma unroll
                for (int b = 0; b < 4; b++) po[b][k] += hacc[t][b] * wf[k];
        }
#pragma unroll
        for (int b = 0; b < 4; b++)
#pragma unroll
            for (int k = 0; k < 4; k++) {
                float v = po[b][k];
#pragma unroll
                for (int off = 32; off >= 1; off >>= 1) v += __shfl_xor(v, off, 64);
                po[b][k] = v;
            }

        if (lane == 0) {
#pragma unroll
            for (int b = 0; b < 4; b++)
#pragma unroll
                for (int k = 0; k < 4; k++)
                    out[((size_t)b * NQRY + q) * 4 + k] = po[b][k] + bp1[k];
        }
        __syncthreads();                 // protect decs before next query
    }
}

// ---------------------------------------------------------------------------
extern "C" void kernel_launch(void* const* d_in, const int* in_sizes, int n_in,
                              void* d_out, int out_size, void* d_ws, size_t ws_size,
                              hipStream_t stream) {
    const float* lat  = (const float*)d_in[0];
    const float* rnd  = (const float*)d_in[1];
    const float* qc   = (const float*)d_in[2];
    const int*   src0 = (const int*)d_in[3];
    const int*   qry0 = (const int*)d_in[4];
    const int*   src1 = (const int*)d_in[5];
    const int*   qry1 = (const int*)d_in[6];
    const float* Wk0 = (const float*)d_in[7],  *bk0 = (const float*)d_in[8];
    const float* Wk1 = (const float*)d_in[9],  *bk1 = (const float*)d_in[10];
    const float* Wk2 = (const float*)d_in[11], *bk2 = (const float*)d_in[12];
    const float* Wsw0 = (const float*)d_in[13], *bsw0 = (const float*)d_in[14];
    const float* Wsw1 = (const float*)d_in[15], *bsw1 = (const float*)d_in[16];
    const float* Wp0 = (const float*)d_in[17], *bp0 = (const float*)d_in[18];
    const float* Wp1 = (const float*)d_in[19], *bp1 = (const float*)d_in[20];

    const int E0 = in_sizes[3];
    const int E1 = in_sizes[5];

    fused_kernel<<<NQRY / QPW, 64, 0, stream>>>(
        lat, rnd, qc, src0, qry0, E0, src1, qry1, E1,
        Wk0, bk0, Wk1, bk1, Wk2, bk2,
        Wsw0, bsw0, Wsw1, bsw1, Wp0, bp0, Wp1, bp1,
        (float*)d_out);
}